// Round 7
// baseline (484.208 us; speedup 1.0000x reference)
//
#include <hip/hip_runtime.h>
#include <hip/hip_bf16.h>

#define T_SEQ   2048
#define HIDDEN  2048
#define NUM_H   32
#define NUM_KV  8
#define HD      128
#define Q_SIZE  4096
#define QKV_N   6144

typedef __bf16 bf16;
typedef __bf16 bf16x8 __attribute__((ext_vector_type(8)));
typedef __bf16 bf16x4 __attribute__((ext_vector_type(4)));
typedef __bf16 bf16x2 __attribute__((ext_vector_type(2)));
typedef float  floatx4 __attribute__((ext_vector_type(4)));

#define GLOBAL_AS(p) ((const __attribute__((address_space(1))) void*)(p))
#define LDS_AS(p)    ((__attribute__((address_space(3))) void*)(p))

// ---------------------------------------------------------------------------
// fp32 -> bf16 canonicalization, fully coalesced: 4 elems (1 float4) / thread.
// Ranges: hidden 4194304 | wqkv 12582912 | wo 8388608 | qnw 128 | knw 128.
// ---------------------------------------------------------------------------
__global__ __launch_bounds__(256) void convert_all(
    const float* __restrict__ h, const float* __restrict__ wq,
    const float* __restrict__ wo_, const float* __restrict__ qn,
    const float* __restrict__ kn,
    bf16* __restrict__ hb, bf16* __restrict__ wqb, bf16* __restrict__ wob,
    bf16* __restrict__ qnb, bf16* __restrict__ knb)
{
    long e = ((long)blockIdx.x * 256 + threadIdx.x) * 4;
    const float* src; bf16* dst; long off;
    if      (e < 4194304)  { src = h;   dst = hb;  off = e; }
    else if (e < 16777216) { src = wq;  dst = wqb; off = e - 4194304; }
    else if (e < 25165824) { src = wo_; dst = wob; off = e - 16777216; }
    else if (e < 25165952) { src = qn;  dst = qnb; off = e - 25165824; }
    else if (e < 25166080) { src = kn;  dst = knb; off = e - 25165952; }
    else return;

    floatx4 v = *(const floatx4*)(src + off);
    bf16x4 o;
    #pragma unroll
    for (int i = 0; i < 4; ++i) o[i] = (bf16)v[i];
    *(bf16x4*)(dst + off) = o;
}

// ---------------------------------------------------------------------------
// NT GEMM 128x128 (m97 structure): C[M,N] = A[M,K]*B[N,K]^T, bf16 out.
// Used for the QKV projection (grid 16x48 = 768 blocks = 3/CU).
// ---------------------------------------------------------------------------
__global__ __launch_bounds__(256) void gemm_bt(
    const bf16* __restrict__ A, const bf16* __restrict__ B,
    bf16* __restrict__ C, int M, int N, int K, int lda)
{
    __shared__ bf16 As[128 * 32];
    __shared__ bf16 Bs[128 * 32];

    const int tid  = threadIdx.x;
    const int wave = tid >> 6, lane = tid & 63;
    const int quad = lane >> 4, l16 = lane & 15;
    const int wm = (wave & 1) * 64, wn = (wave >> 1) * 64;
    const long baseM = (long)blockIdx.x * 128;
    const long baseN = (long)blockIdx.y * 128;

    const int  srow = wave * 16 + (lane >> 2);
    const int  scol = (lane & 3) * 8;
    const long aoff0 = (baseM + srow) * (long)lda + scol;
    const long aoff1 = (baseM + 64 + srow) * (long)lda + scol;
    const long boff0 = (baseN + srow) * (long)K + scol;
    const long boff1 = (baseN + 64 + srow) * (long)K + scol;
    const int  lds0 = wave * 512;
    const int  lds1 = 2048 + wave * 512;

    floatx4 acc[4][4] = {};

    for (int k0 = 0; k0 < K; k0 += 32) {
        __builtin_amdgcn_global_load_lds(GLOBAL_AS(A + aoff0 + k0), LDS_AS(As + lds0), 16, 0, 0);
        __builtin_amdgcn_global_load_lds(GLOBAL_AS(A + aoff1 + k0), LDS_AS(As + lds1), 16, 0, 0);
        __builtin_amdgcn_global_load_lds(GLOBAL_AS(B + boff0 + k0), LDS_AS(Bs + lds0), 16, 0, 0);
        __builtin_amdgcn_global_load_lds(GLOBAL_AS(B + boff1 + k0), LDS_AS(Bs + lds1), 16, 0, 0);
        __syncthreads();

        bf16x8 af[4], bfr[4];
        #pragma unroll
        for (int i = 0; i < 4; ++i)
            af[i] = *(const bf16x8*)(As + (wm + i * 16 + l16) * 32 + quad * 8);
        #pragma unroll
        for (int j = 0; j < 4; ++j)
            bfr[j] = *(const bf16x8*)(Bs + (wn + j * 16 + l16) * 32 + quad * 8);

        #pragma unroll
        for (int i = 0; i < 4; ++i)
            #pragma unroll
            for (int j = 0; j < 4; ++j)
                acc[i][j] = __builtin_amdgcn_mfma_f32_16x16x32_bf16(af[i], bfr[j], acc[i][j], 0, 0, 0);
        __syncthreads();
    }

    #pragma unroll
    for (int i = 0; i < 4; ++i)
        #pragma unroll
        for (int j = 0; j < 4; ++j)
            #pragma unroll
            for (int r = 0; r < 4; ++r) {
                long row = baseM + wm + i * 16 + quad * 4 + r;
                long col = baseN + wn + j * 16 + l16;
                C[row * (long)N + col] = (bf16)acc[i][j][r];
            }
}

// ---------------------------------------------------------------------------
// o-proj GEMM with K split across blockIdx.z (2 halves): fp32 partials to
// p0 / p1. Grid (16,16,2) = 512 blocks = 2/CU with full 128x128 tiles.
// ---------------------------------------------------------------------------
__global__ __launch_bounds__(256) void gemm_bt_split(
    const bf16* __restrict__ A, const bf16* __restrict__ B,
    float* __restrict__ p0, float* __restrict__ p1,
    int M, int N, int K, int lda, int Kh)
{
    __shared__ bf16 As[128 * 32];
    __shared__ bf16 Bs[128 * 32];

    const int tid  = threadIdx.x;
    const int wave = tid >> 6, lane = tid & 63;
    const int quad = lane >> 4, l16 = lane & 15;
    const int wm = (wave & 1) * 64, wn = (wave >> 1) * 64;
    const long baseM = (long)blockIdx.x * 128;
    const long baseN = (long)blockIdx.y * 128;
    const int  koff  = blockIdx.z * Kh;
    float* Cout = blockIdx.z ? p1 : p0;

    const int  srow = wave * 16 + (lane >> 2);
    const int  scol = (lane & 3) * 8;
    const long aoff0 = (baseM + srow) * (long)lda + scol + koff;
    const long aoff1 = (baseM + 64 + srow) * (long)lda + scol + koff;
    const long boff0 = (baseN + srow) * (long)K + scol + koff;
    const long boff1 = (baseN + 64 + srow) * (long)K + scol + koff;
    const int  lds0 = wave * 512;
    const int  lds1 = 2048 + wave * 512;

    floatx4 acc[4][4] = {};

    for (int k0 = 0; k0 < Kh; k0 += 32) {
        __builtin_amdgcn_global_load_lds(GLOBAL_AS(A + aoff0 + k0), LDS_AS(As + lds0), 16, 0, 0);
        __builtin_amdgcn_global_load_lds(GLOBAL_AS(A + aoff1 + k0), LDS_AS(As + lds1), 16, 0, 0);
        __builtin_amdgcn_global_load_lds(GLOBAL_AS(B + boff0 + k0), LDS_AS(Bs + lds0), 16, 0, 0);
        __builtin_amdgcn_global_load_lds(GLOBAL_AS(B + boff1 + k0), LDS_AS(Bs + lds1), 16, 0, 0);
        __syncthreads();

        bf16x8 af[4], bfr[4];
        #pragma unroll
        for (int i = 0; i < 4; ++i)
            af[i] = *(const bf16x8*)(As + (wm + i * 16 + l16) * 32 + quad * 8);
        #pragma unroll
        for (int j = 0; j < 4; ++j)
            bfr[j] = *(const bf16x8*)(Bs + (wn + j * 16 + l16) * 32 + quad * 8);

        #pragma unroll
        for (int i = 0; i < 4; ++i)
            #pragma unroll
            for (int j = 0; j < 4; ++j)
                acc[i][j] = __builtin_amdgcn_mfma_f32_16x16x32_bf16(af[i], bfr[j], acc[i][j], 0, 0, 0);
        __syncthreads();
    }

    #pragma unroll
    for (int i = 0; i < 4; ++i)
        #pragma unroll
        for (int j = 0; j < 4; ++j)
            #pragma unroll
            for (int r = 0; r < 4; ++r) {
                long row = baseM + wm + i * 16 + quad * 4 + r;
                long col = baseN + wn + j * 16 + l16;
                Cout[row * (long)N + col] = acc[i][j][r];
            }
}

// out = p0 + p1 (in place over p0 == d_out), fp32 float4.
__global__ __launch_bounds__(256) void add_out(float* __restrict__ p0,
                                               const float* __restrict__ p1)
{
    long i = ((long)blockIdx.x * 256 + threadIdx.x) * 4;
    floatx4 a = *(const floatx4*)(p0 + i);
    floatx4 b = *(const floatx4*)(p1 + i);
    *(floatx4*)(p0 + i) = a + b;
}

// ---------------------------------------------------------------------------
// In-place RMSNorm + RoPE on q/k sections of qkv[t][6144], vectorized:
// lane L holds elems (2L, 2L+1); RoPE partner (j <-> j+64) via shfl_xor(32).
// ---------------------------------------------------------------------------
__global__ __launch_bounds__(256) void qkv_post(
    bf16* __restrict__ qkv, const int* __restrict__ positions,
    const bf16* __restrict__ qnw, const bf16* __restrict__ knw)
{
    const int t = blockIdx.x;
    const int tid = threadIdx.x, wave = tid >> 6, lane = tid & 63;
    const float pos = (float)positions[t];

    const int   j0 = (2 * lane) & 63;          // freq index of this lane's pair
    const float inv0 = expf(-(float)j0 * (float)(9.210340371976184 / 64.0));
    const float inv1 = expf(-(float)(j0 + 1) * (float)(9.210340371976184 / 64.0));
    float sn0, cs0, sn1, cs1;
    sincosf(pos * inv0, &sn0, &cs0);
    sincosf(pos * inv1, &sn1, &cs1);
    const float sgn = (lane < 32) ? -1.f : 1.f;

    bf16* row = qkv + (long)t * QKV_N;

    for (int u = wave; u < 40; u += 4) {
        bf16* p       = (u < 32) ? row + u * HD : row + Q_SIZE + (u - 32) * HD;
        const bf16* w = (u < 32) ? qnw : knw;
        bf16x2 xv = *(const bf16x2*)(p + 2 * lane);
        float x0 = (float)xv[0], x1 = (float)xv[1];
        float ss = x0 * x0 + x1 * x1;
        #pragma unroll
        for (int m = 32; m; m >>= 1) ss += __shfl_xor(ss, m);
        float rr = rsqrtf(ss * (1.f / 128.f) + 1e-6f);
        bf16x2 wv = *(const bf16x2*)(w + 2 * lane);
        float xh0 = x0 * rr * (float)wv[0];
        float xh1 = x1 * rr * (float)wv[1];
        float y0 = __shfl_xor(xh0, 32);
        float y1 = __shfl_xor(xh1, 32);
        bf16x2 o;
        o[0] = (bf16)(xh0 * cs0 + sgn * y0 * sn0);
        o[1] = (bf16)(xh1 * cs1 + sgn * y1 * sn1);
        *(bf16x2*)(p + 2 * lane) = o;
    }
}

// ---------------------------------------------------------------------------
// V transpose: vt[kvh][d][t] from qkv[t][5120+kvh*128+d].
// ---------------------------------------------------------------------------
__global__ __launch_bounds__(256) void vtrans(const bf16* __restrict__ qkv,
                                              bf16* __restrict__ vt)
{
    __shared__ bf16 tile[64][136];
    const int t0 = blockIdx.x * 64, kvh = blockIdx.y, tid = threadIdx.x;

    const int rl = tid >> 4, c8 = (tid & 15) * 8;
    const bf16* src = qkv + (long)t0 * QKV_N + 5120 + kvh * HD;
    #pragma unroll
    for (int it = 0; it < 4; ++it) {
        int r = it * 16 + rl;
        *(bf16x8*)(&tile[r][c8]) = *(const bf16x8*)(src + (long)r * QKV_N + c8);
    }
    __syncthreads();

    const int d = tid >> 1, tb = (tid & 1) * 32;
    bf16* dst = vt + ((long)kvh * HD + d) * T_SEQ + t0 + tb;
    #pragma unroll
    for (int it = 0; it < 4; ++it) {
        bf16x8 v;
        #pragma unroll
        for (int j = 0; j < 8; ++j) v[j] = tile[tb + it * 8 + j][d];
        *(bf16x8*)(dst + it * 8) = v;
    }
}

// ---------------------------------------------------------------------------
// attn5: paired-tile causal flash attention, fixed-max softmax (|s| <= 11.32
// since ||q||=||k||=sqrt(128)), S^T = K*Q^T layout (vectorized P stores,
// per-lane row sums). K: LDS double-buffered (1 barrier/iter, async
// global_load_lds prefetch). V: loaded DIRECTLY from global vt (L2-resident)
// as the MFMA B-operand — no LDS round trip, halves LDS-pipe traffic and
// staging DMA. LDS 41 KB -> 3 blocks/CU.
// ---------------------------------------------------------------------------
#define PSTR 72
__global__ __launch_bounds__(256) void attn5(bf16* qkv, const bf16* __restrict__ vt)
{
    __shared__ bf16 Ks[2][64 * 128];   // [kt-row][d], 16B chunk c at c^(row&15)
    __shared__ bf16 Ps[4][16 * PSTR];  // per-wave P tile (A then B sequentially)

    const int tid  = threadIdx.x, wave = tid >> 6, lane = tid & 63;
    const int quad = lane >> 4, l16 = lane & 15;
    const int h = blockIdx.y, kvh = h >> 2;
    const int iB = blockIdx.x;        // small q-tile
    const int iA = 31 - iB;           // large q-tile
    const int q0A = iA * 64, q0B = iB * 64;

    const float C1 = 0.12753236f;     // 128^-0.5 * log2(e)
    const float C2 = 17.312340f;      // 12 * log2(e)

    bf16x8 qfA[4], qfB[4];
    {
        const bf16* qa = qkv + (long)(q0A + wave * 16 + l16) * QKV_N + h * HD + quad * 8;
        const bf16* qb = qkv + (long)(q0B + wave * 16 + l16) * QKV_N + h * HD + quad * 8;
        #pragma unroll
        for (int ks = 0; ks < 4; ++ks) {
            qfA[ks] = *(const bf16x8*)(qa + ks * 32);
            qfB[ks] = *(const bf16x8*)(qb + ks * 32);
        }
    }

    floatx4 oaccA[8] = {}, oaccB[8] = {};
    float lsA = 0.f, lsB = 0.f;

    const int krl = lane >> 4, kc = lane & 15;
    const int kswz = (kc ^ (wave * 4 + krl)) * 8;
    const bf16* kg0 = qkv + Q_SIZE + kvh * HD;
    const bf16* vb0 = vt + ((long)(kvh * HD + l16)) * T_SEQ + quad * 8;  // + vj*16*T + k0 + ks2*32

    auto stageK = [&](int p, int kt) {
        const bf16* kg = kg0 + (long)kt * 64 * QKV_N;
        #pragma unroll
        for (int it = 0; it < 4; ++it) {
            const int rK = it * 16 + wave * 4 + krl;
            __builtin_amdgcn_global_load_lds(GLOBAL_AS(kg + (long)rK * QKV_N + kswz),
                                             LDS_AS(&Ks[p][it * 2048 + wave * 512]), 16, 0, 0);
        }
    };

    stageK(0, 0);

    for (int kt = 0; kt <= iA; ++kt) {
        const int p = kt & 1;
        __syncthreads();                       // Ks[p] ready; Ks[p^1] readers done
        if (kt < iA) stageK(p ^ 1, kt + 1);    // async prefetch, drains at next barrier

        const int k0 = kt * 64;
        const bool doB = (kt <= iB);

        // S^T = K Q^T  (rows = kt, cols = q)
        floatx4 sTA[4] = {}, sTB[4] = {};
        #pragma unroll
        for (int j2 = 0; j2 < 4; ++j2)
            #pragma unroll
            for (int ks = 0; ks < 4; ++ks) {
                bf16x8 kf = *(const bf16x8*)(&Ks[p][(j2 * 16 + l16) * 128 + (((ks * 4 + quad) ^ l16) * 8)]);
                sTA[j2] = __builtin_amdgcn_mfma_f32_16x16x32_bf16(kf, qfA[ks], sTA[j2], 0, 0, 0);
                if (doB)
                    sTB[j2] = __builtin_amdgcn_mfma_f32_16x16x32_bf16(kf, qfB[ks], sTB[j2], 0, 0, 0);
            }

        bf16x8 paA[2], paB[2];
        {
            const int qg = q0A + wave * 16 + l16;
            const bool diag = (kt == iA);
            #pragma unroll
            for (int j2 = 0; j2 < 4; ++j2) {
                bf16x4 pk;
                #pragma unroll
                for (int r = 0; r < 4; ++r) {
                    float e = exp2f(sTA[j2][r] * C1 - C2);
                    if (diag && (k0 + j2 * 16 + quad * 4 + r > qg)) e = 0.f;
                    lsA += e;
                    pk[r] = (bf16)e;
                }
                *(bf16x4*)(&Ps[wave][l16 * PSTR + j2 * 16 + quad * 4]) = pk;
            }
            #pragma unroll
            for (int ks2 = 0; ks2 < 2; ++ks2)
                paA[ks2] = *(const bf16x8*)(&Ps[wave][l16 * PSTR + ks2 * 32 + quad * 8]);
        }
        if (doB) {
            const int qg = q0B + wave * 16 + l16;
            const bool diag = (kt == iB);
            #pragma unroll
            for (int j2 = 0; j2 < 4; ++j2) {
                bf16x4 pk;
                #pragma unroll
                for (int r = 0; r < 4; ++r) {
                    float e = exp2f(sTB[j2][r] * C1 - C2);
                    if (diag && (k0 + j2 * 16 + quad * 4 + r > qg)) e = 0.f;
                    lsB += e;
                    pk[r] = (bf16)e;
                }
                *(bf16x4*)(&Ps[wave][l16 * PSTR + j2 * 16 + quad * 4]) = pk;
            }
            #pragma unroll
            for (int ks2 = 0; ks2 < 2; ++ks2)
                paB[ks2] = *(const bf16x8*)(&Ps[wave][l16 * PSTR + ks2 * 32 + quad * 8]);
        }

        // O += P V ; V fragments direct from global (B-operand), shared A/B
        #pragma unroll
        for (int ks2 = 0; ks2 < 2; ++ks2)
            #pragma unroll
            for (int vj = 0; vj < 8; ++vj) {
                bf16x8 vb = *(const bf16x8*)(vb0 + (long)vj * 16 * T_SEQ + k0 + ks2 * 32);
                oaccA[vj] = __builtin_amdgcn_mfma_f32_16x16x32_bf16(paA[ks2], vb, oaccA[vj], 0, 0, 0);
                if (doB)
                    oaccB[vj] = __builtin_amdgcn_mfma_f32_16x16x32_bf16(paB[ks2], vb, oaccB[vj], 0, 0, 0);
            }
    }

    // row sums: lane l16 holds q-row l16's partial; reduce quads, redistribute
    lsA += __shfl_xor(lsA, 16); lsA += __shfl_xor(lsA, 32);
    lsB += __shfl_xor(lsB, 16); lsB += __shfl_xor(lsB, 32);
    float rA[4], rB[4];
    #pragma unroll
    for (int r = 0; r < 4; ++r) {
        rA[r] = 1.f / __shfl(lsA, quad * 4 + r);
        rB[r] = 1.f / __shfl(lsB, quad * 4 + r);
    }

    #pragma unroll
    for (int vj = 0; vj < 8; ++vj)
        #pragma unroll
        for (int r = 0; r < 4; ++r) {
            const long rowA = q0A + wave * 16 + quad * 4 + r;
            const long rowB = q0B + wave * 16 + quad * 4 + r;
            qkv[rowA * (long)QKV_N + h * HD + vj * 16 + l16] = (bf16)(oaccA[vj][r] * rA[r]);
            qkv[rowB * (long)QKV_N + h * HD + vj * 16 + l16] = (bf16)(oaccB[vj][r] * rB[r]);
        }
}

// ---------------------------------------------------------------------------
extern "C" void kernel_launch(void* const* d_in, const int* in_sizes, int n_in,
                              void* d_out, int out_size, void* d_ws, size_t ws_size,
                              hipStream_t stream)
{
    const int* positions = (const int*)d_in[0];

    char* ws = (char*)d_ws;
    bf16*  qkv = (bf16*)(ws);              // [2048][6144]  25165824 B
    bf16*  hb  = (bf16*)(ws + 25165824);   // [2048][2048]   8388608 B (dead after gemm1)
    bf16*  vt  = hb;                       // [8][128][2048] 4194304 B (aliases hb)
    float* p1  = (float*)(ws + 25165824);  // 16777216 B (aliases hb/vt/wqb-front; live only after attn)
    bf16*  wqb = (bf16*)(ws + 33554432);   // [6144][2048]  25165824 B (dead after gemm1)
    bf16*  wob = (bf16*)(ws + 58720256);   // [2048][4096]  16777216 B
    bf16*  qnb = (bf16*)(ws + 75497472);
    bf16*  knb = (bf16*)(ws + 75497728);

    dim3 blk(256);
    convert_all<<<dim3(24577), blk, 0, stream>>>(
        (const float*)d_in[1], (const float*)d_in[2], (const float*)d_in[3],
        (const float*)d_in[4], (const float*)d_in[5],
        hb, wqb, wob, qnb, knb);

    gemm_bt<<<dim3(T_SEQ / 128, QKV_N / 128), blk, 0, stream>>>(
        hb, wqb, qkv, T_SEQ, QKV_N, HIDDEN, HIDDEN);
    vtrans<<<dim3(T_SEQ / 64, NUM_KV), blk, 0, stream>>>(qkv, vt);
    qkv_post<<<dim3(T_SEQ), blk, 0, stream>>>(qkv, positions, qnb, knb);
    attn5<<<dim3(16, NUM_H), blk, 0, stream>>>(qkv, vt);
    gemm_bt_split<<<dim3(T_SEQ / 128, HIDDEN / 128, 2), blk, 0, stream>>>(
        qkv, wob, (float*)d_out, p1, T_SEQ, HIDDEN, Q_SIZE, QKV_N, Q_SIZE / 2);
    add_out<<<dim3(4096), blk, 0, stream>>>((float*)d_out, p1);
}